// Round 8
// baseline (1498.091 us; speedup 1.0000x reference)
//
#include <hip/hip_runtime.h>

// DeepAR forward: B=32, L_IN=336, L_OUT=48, N=512, COV=4, EMB=32, H=64
// T=383 steps, 16384 independent sequences.
// R8: layer-pipelined wave specialization. 256 WGs x 512 thr (1 WG/CU),
// 64 seqs/WG. Waves 0-3: layer 0 (weights in regs); waves 4-7: layer 1
// (weights from LDS). Super-step s: L0 makes h0(s) while L1 makes h1(s-1)
// concurrently (independent) -> ONE barrier/step (R3 had 3; its ~30% idle
// was barrier convoy). L1's LDS weight reads overlap L0's VALU/MFMA on the
// same SIMD (wave i -> SIMD i%4: each SIMD gets one L0 + one L1 wave).
// h0,h1 double-buffered in LDS; head in L0 waves at lag 2 (t = s-2).
// Activation math = R3's exact (10 trans/elem; R7 proved trans ~= VALU rate,
// so fewer-trans-more-VALU is a loss). No spills at ~200 regs (2 waves/SIMD).

#define NSTEP 385   // super-steps: L0 active s<=382, L1 s in [1,383], head s in [337,384]

typedef __attribute__((ext_vector_type(8))) short short8;
typedef __attribute__((ext_vector_type(4))) float floatx4;

static __device__ __forceinline__ unsigned short f2bf(float f){   // RNE
  union { float f; unsigned u; } v; v.f = f;
  unsigned u = v.u + 0x7fffu + ((v.u >> 16) & 1u);
  return (unsigned short)(u >> 16);
}
static __device__ __forceinline__ unsigned short f2bf_fast(float f){  // round-half-up
  union { float f; unsigned u; } v; v.f = f;
  return (unsigned short)((v.u + 0x8000u) >> 16);
}
static __device__ __forceinline__ float bf2f(unsigned short b){
  union { unsigned u; float f; } v; v.u = ((unsigned)b) << 16; return v.f;
}
static __device__ __forceinline__ float fsig(float x){
  return __builtin_amdgcn_rcpf(1.f + __expf(-x));
}
static __device__ __forceinline__ float ftanh(float x){
  return 1.f - 2.f * __builtin_amdgcn_rcpf(1.f + __expf(2.f * x));
}

__global__ __launch_bounds__(512, 2) void deepar_kernel(
    const float* __restrict__ hist, const float* __restrict__ fut,
    const float* __restrict__ embW, const float* __restrict__ embB,
    const float* __restrict__ Wih0, const float* __restrict__ Whh0,
    const float* __restrict__ bih0, const float* __restrict__ bhh0,
    const float* __restrict__ Wih1, const float* __restrict__ Whh1,
    const float* __restrict__ bih1, const float* __restrict__ bhh1,
    const float* __restrict__ headW, const float* __restrict__ headB,
    float* __restrict__ outp)
{
  const int tid  = threadIdx.x;
  const int lane = tid & 63;
  const int w    = tid >> 6;          // wave 0..7
  const bool isL0 = (w < 4);
  const int sub  = isL0 ? w : (w - 4);  // unit/gate-column sub-block 0..3
  const int l15  = lane & 15;
  const int quad = lane >> 4;
  const int koff = quad * 8;
  const int jcol = sub * 16 + l15;    // hidden-unit col this lane owns

  const int b  = blockIdx.x >> 3;          // batch
  const int n0 = (blockIdx.x & 7) * 64;    // first series index (64 seqs/WG)

  // H0[buf][seq 64][88]: cols 0..63 h0 | 64..68 inputs (prev,cov) | 69..87 pad
  //   stride 88 shorts = 44 dwords: l15 & l15+8 alias 2-way only (free).
  // H1[buf][seq 64][72]: cols 0..63 h1 | pad. stride 36 dwords: 2-way only.
  __shared__ __align__(16) unsigned short H0[2][64][88];
  __shared__ __align__(16) unsigned short H1[2][64][72];
  __shared__ __align__(16) unsigned short W1s[64 * 512]; // 64 frags x (64 lanes x 8 shorts)
  __shared__ float HW[128];

  for (int i = tid; i < 2 * 64 * 88; i += 512) ((unsigned short*)H0)[i] = 0;
  for (int i = tid; i < 2 * 64 * 72; i += 512) ((unsigned short*)H1)[i] = 0;
  if (tid < 128) HW[tid] = headW[tid];
  const float hb0 = headB[0], hb1 = headB[1];

  // ---- weight prep (per wave role) ----
  // B-frag (16x16x32): lane holds B^T[n=l15][k=koff+j], j=0..7
  short8 bf0[4][3];   // L0 waves only: [gate][kf]; kf0,1=Whh0, kf2=input cols
  float  bia[4];      // bias acc-init (bi0 for L0 waves, bi1 for L1 waves)
  if (isL0){
    #pragma unroll
    for (int g = 0; g < 4; ++g){
      const int r = g * 64 + sub * 16 + l15;    // gate row 0..255
      float u = 0.f, bb = bih0[r] + bhh0[r];
      #pragma unroll
      for (int e = 0; e < 32; ++e){
        float wval = Wih0[r * 36 + e];
        u  += wval * embW[e];
        bb += wval * embB[e];
      }
      bia[g] = bb;
      #pragma unroll
      for (int kf = 0; kf < 2; ++kf)
        #pragma unroll
        for (int j = 0; j < 8; ++j)
          bf0[g][kf][j] = (short)f2bf(Whh0[r * 64 + kf * 32 + koff + j]);
      #pragma unroll
      for (int j = 0; j < 8; ++j){
        int kk = koff + j;              // input col = 64+kk in H0 row
        float v = 0.f;
        if (kk == 0) v = u;                               // prev -> u[r]
        else if (kk >= 1 && kk <= 4) v = Wih0[r * 36 + 32 + (kk - 1)];
        bf0[g][2][j] = (short)f2bf(v);
      }
    }
  } else {
    #pragma unroll
    for (int g = 0; g < 4; ++g){
      const int r = g * 64 + sub * 16 + l15;
      bia[g] = bih1[r] + bhh1[r];
      #pragma unroll
      for (int kf = 0; kf < 4; ++kf){
        const float* src = (kf < 2) ? (Wih1 + r * 64 + kf * 32)
                                    : (Whh1 + r * 64 + (kf - 2) * 32);
        short8 wv8;
        #pragma unroll
        for (int j = 0; j < 8; ++j)
          wv8[j] = (short)f2bf(src[koff + j]);
        *(short8*)&W1s[((sub * 16 + g * 4 + kf) * 64 + lane) * 8] = wv8;
      }
    }
  }

  // ---- input staging: prev tid 0..63 -> col 64; cov tid 64..319 -> cols 65..68
  const bool isPrev = (tid < 64);
  const bool isCov  = (tid >= 64 && tid < 320);
  const bool act    = isPrev || isCov;
  int ss = 0, cc = 0;
  if (isPrev){ ss = tid; cc = 0; }
  if (isCov) { ss = (tid - 64) >> 2; cc = 1 + ((tid - 64) & 3); }
  const int myN = n0 + ss;

  auto loadSlab = [&](int tt) -> float {
    if (isPrev){
      int l = tt; if (l > 383) l = 383;
      return (l < 336) ? hist[(((size_t)b * 336 + l) * 512 + myN) * 5]
                       : fut [(((size_t)b * 48 + (l - 336)) * 512 + myN) * 5];
    } else if (isCov){
      int l = tt + 1; if (l > 383) l = 383;
      return (l < 336) ? hist[(((size_t)b * 336 + l) * 512 + myN) * 5 + cc]
                       : fut [(((size_t)b * 48 + (l - 336)) * 512 + myN) * 5 + cc];
    }
    return 0.f;
  };

  float cst[16];        // c-state: L0 waves -> c0, L1 waves -> c1
  #pragma unroll
  for (int i = 0; i < 16; ++i) cst[i] = 0.f;

  __syncthreads();                               // zeros + W1s visible
  if (act) H0[1][ss][64 + cc] = f2bf(loadSlab(0));  // in(0) -> read-buf of s=0
  float rIn = loadSlab(1);                       // in(1) staged during s=0
  __syncthreads();

  for (int s = 0; s < NSTEP; ++s){
    const int rb = (s + 1) & 1;   // h0(s-1) | in(s) ; also h1(s-2) buffer
    const int wb = s & 1;         // h0(s) | in(s+1) ; h1(s-1) buffer

    if (isL0){
      // ============ layer 0: h0(s) from h0(s-1), in(s) ============
      if (s <= 382){
        floatx4 acc[4][4];
        #pragma unroll
        for (int g = 0; g < 4; ++g)
          #pragma unroll
          for (int mt = 0; mt < 4; ++mt){
            floatx4 binit = { bia[g], bia[g], bia[g], bia[g] };
            acc[g][mt] = binit;
          }
        #pragma unroll
        for (int mt = 0; mt < 4; ++mt){
          #pragma unroll
          for (int kf = 0; kf < 2; ++kf){
            short8 af = *(const short8*)&H0[rb][mt * 16 + l15][kf * 32 + koff];
            #pragma unroll
            for (int g = 0; g < 4; ++g)
              acc[g][mt] = __builtin_amdgcn_mfma_f32_16x16x32_bf16(af, bf0[g][kf], acc[g][mt], 0, 0, 0);
          }
          short8 afin = { 0,0,0,0,0,0,0,0 };
          if (quad == 0) afin = *(const short8*)&H0[rb][mt * 16 + l15][64];
          #pragma unroll
          for (int g = 0; g < 4; ++g)
            acc[g][mt] = __builtin_amdgcn_mfma_f32_16x16x32_bf16(afin, bf0[g][2], acc[g][mt], 0, 0, 0);
        }
        #pragma unroll
        for (int mt = 0; mt < 4; ++mt)
          #pragma unroll
          for (int q = 0; q < 4; ++q){
            int idx = mt * 4 + q;
            float iv = acc[0][mt][q], fv = acc[1][mt][q];
            float gv = acc[2][mt][q], ov = acc[3][mt][q];
            float c = fsig(fv) * cst[idx] + fsig(iv) * ftanh(gv);
            cst[idx] = c;
            H0[wb][mt * 16 + quad * 4 + q][jcol] =
                f2bf_fast(fsig(ov) * ftanh(c));               // h0(s)
          }
      }
      // ============ head (L0 waves, lag 2: t = s-2, last 48 only) ========
      if (s >= 337){
        const int hs = tid >> 2, outc = (tid >> 1) & 1, part = tid & 1;
        float p = 0.f;
        #pragma unroll
        for (int ch = 0; ch < 4; ++ch){
          short8 hv = *(const short8*)&H1[rb][hs][part * 32 + ch * 8];
          #pragma unroll
          for (int j = 0; j < 8; ++j)
            p += fmaxf(bf2f((unsigned short)hv[j]), 0.f) * HW[outc * 64 + part * 32 + ch * 8 + j];
        }
        p += __shfl_xor(p, 1);
        if (part == 0){
          float val;
          if (outc == 0) val = p + hb0;
          else {
            float x = p + hb1;   // softplus, stable
            val = fmaxf(x, 0.f) + __logf(1.f + __expf(-fabsf(x)));
          }
          outp[(((size_t)b * 48 + (s - 337)) * 512 + (n0 + hs)) * 2 + outc] = val;
        }
      }
    } else {
      // ============ layer 1: h1(s-1) from h0(s-1), h1(s-2) ============
      if (s >= 1 && s <= 383){
        floatx4 acc[4][4];
        #pragma unroll
        for (int g = 0; g < 4; ++g)
          #pragma unroll
          for (int mt = 0; mt < 4; ++mt){
            floatx4 binit = { bia[g], bia[g], bia[g], bia[g] };
            acc[g][mt] = binit;
          }
        #pragma unroll
        for (int kf = 0; kf < 4; ++kf){
          short8 wfr[4];
          #pragma unroll
          for (int g = 0; g < 4; ++g)
            wfr[g] = *(const short8*)&W1s[((sub * 16 + g * 4 + kf) * 64 + lane) * 8];
          #pragma unroll
          for (int mt = 0; mt < 4; ++mt){
            short8 af = (kf < 2)
                ? *(const short8*)&H0[rb][mt * 16 + l15][kf * 32 + koff]
                : *(const short8*)&H1[rb][mt * 16 + l15][(kf - 2) * 32 + koff];
            #pragma unroll
            for (int g = 0; g < 4; ++g)
              acc[g][mt] = __builtin_amdgcn_mfma_f32_16x16x32_bf16(af, wfr[g], acc[g][mt], 0, 0, 0);
          }
        }
        #pragma unroll
        for (int mt = 0; mt < 4; ++mt)
          #pragma unroll
          for (int q = 0; q < 4; ++q){
            int idx = mt * 4 + q;
            float iv = acc[0][mt][q], fv = acc[1][mt][q];
            float gv = acc[2][mt][q], ov = acc[3][mt][q];
            float c = fsig(fv) * cst[idx] + fsig(iv) * ftanh(gv);
            cst[idx] = c;
            H1[wb][mt * 16 + quad * 4 + q][jcol] =
                f2bf_fast(fsig(ov) * ftanh(c));               // h1(s-1)
          }
      }
    }

    // in(s+1) -> write buffer (read next step); then ONE barrier.
    if (act) H0[wb][ss][64 + cc] = f2bf_fast(rIn);
    rIn = loadSlab(s + 2);
    __syncthreads();
  }
}

extern "C" void kernel_launch(void* const* d_in, const int* in_sizes, int n_in,
                              void* d_out, int out_size, void* d_ws, size_t ws_size,
                              hipStream_t stream) {
  (void)in_sizes; (void)n_in; (void)out_size; (void)d_ws; (void)ws_size;
  deepar_kernel<<<dim3(256), dim3(512), 0, stream>>>(
      (const float*)d_in[0],  (const float*)d_in[1],
      (const float*)d_in[2],  (const float*)d_in[3],
      (const float*)d_in[4],  (const float*)d_in[5],
      (const float*)d_in[6],  (const float*)d_in[7],
      (const float*)d_in[8],  (const float*)d_in[9],
      (const float*)d_in[10], (const float*)d_in[11],
      (const float*)d_in[12], (const float*)d_in[13],
      (float*)d_out);
}